// Round 5
// baseline (3940.354 us; speedup 1.0000x reference)
//
#include <hip/hip_runtime.h>
#include <limits.h>

// ---------------------------------------------------------------------------
// ShoppingLSTM: 12-layer LSTM (layer0 own weights, layers1..11 shared),
// B=128, S=256, H=EMB=256, OUT=10.
//
// R5: dataflow pipeline with RMW-free sync. R4's per-tick 16-block
// convergence used same-address global_atomic_add(sc0) -> ~16 serialized
// ~900-cyc round trips = ~6 us/tick (measured 13.5 us/tick, MfmaUtil 4.5%).
// Now each block publishes its own progress word (packed 16-int per-layer
// line, plain coherent store); consumers poll lane-parallel (wave 0,
// lanes 0..47 cover pred/self/anti lines) with __all. x+h fragment loads
// merged into ONE 32-load asm with a single terminal vmcnt(0).
// ---------------------------------------------------------------------------

#define BB 128
#define SS 256
#define LL 12
#define NBLK 192
#define AGENT __HIP_MEMORY_SCOPE_AGENT

typedef _Float16 half8 __attribute__((ext_vector_type(8)));
typedef float f32x4 __attribute__((ext_vector_type(4)));

union U8 { unsigned long long u; _Float16 h[4]; };

__device__ __forceinline__ float sigf(float x) {
    return 1.0f / (1.0f + __expf(-x));
}
__device__ __forceinline__ float tanhf_fast(float x) {
    return 1.0f - 2.0f / (1.0f + __expf(2.0f * x));
}
__device__ __forceinline__ half8 cvt8(const float* p) {
    float4 u = *(const float4*)p;
    float4 v = *(const float4*)(p + 4);
    half8 h;
    h[0] = (_Float16)u.x; h[1] = (_Float16)u.y; h[2] = (_Float16)u.z; h[3] = (_Float16)u.w;
    h[4] = (_Float16)v.x; h[5] = (_Float16)v.y; h[6] = (_Float16)v.z; h[7] = (_Float16)v.w;
    return h;
}
__device__ __forceinline__ int pld(const int* p) {
    return __hip_atomic_load(p, __ATOMIC_RELAXED, AGENT);
}

// ---- batched device-coherent loads: loads + terminal waitcnt in ONE asm ----
// (R3 lesson: outputs must be truly ready at asm exit; "=&v" so async dest
// writes never alias address registers.)
__device__ __forceinline__ void ld8x2(const _Float16* p0, const _Float16* p1,
                                      half8 (&r0)[8], half8 (&r1)[8]) {
    asm volatile(
        "global_load_dwordx4 %0, %16, off sc0 sc1\n\t"
        "global_load_dwordx4 %1, %16, off offset:64 sc0 sc1\n\t"
        "global_load_dwordx4 %2, %16, off offset:128 sc0 sc1\n\t"
        "global_load_dwordx4 %3, %16, off offset:192 sc0 sc1\n\t"
        "global_load_dwordx4 %4, %16, off offset:256 sc0 sc1\n\t"
        "global_load_dwordx4 %5, %16, off offset:320 sc0 sc1\n\t"
        "global_load_dwordx4 %6, %16, off offset:384 sc0 sc1\n\t"
        "global_load_dwordx4 %7, %16, off offset:448 sc0 sc1\n\t"
        "global_load_dwordx4 %8, %17, off sc0 sc1\n\t"
        "global_load_dwordx4 %9, %17, off offset:64 sc0 sc1\n\t"
        "global_load_dwordx4 %10, %17, off offset:128 sc0 sc1\n\t"
        "global_load_dwordx4 %11, %17, off offset:192 sc0 sc1\n\t"
        "global_load_dwordx4 %12, %17, off offset:256 sc0 sc1\n\t"
        "global_load_dwordx4 %13, %17, off offset:320 sc0 sc1\n\t"
        "global_load_dwordx4 %14, %17, off offset:384 sc0 sc1\n\t"
        "global_load_dwordx4 %15, %17, off offset:448 sc0 sc1\n\t"
        "s_waitcnt vmcnt(0)"
        : "=&v"(r0[0]), "=&v"(r0[1]), "=&v"(r0[2]), "=&v"(r0[3]),
          "=&v"(r0[4]), "=&v"(r0[5]), "=&v"(r0[6]), "=&v"(r0[7]),
          "=&v"(r1[0]), "=&v"(r1[1]), "=&v"(r1[2]), "=&v"(r1[3]),
          "=&v"(r1[4]), "=&v"(r1[5]), "=&v"(r1[6]), "=&v"(r1[7])
        : "v"(p0), "v"(p1)
        : "memory");
}
// 32 loads from 4 bases (x Mtile0/1, h Mtile0/1), single drain.
__device__ __forceinline__ void ld8x4(const _Float16* px0, const _Float16* px1,
                                      const _Float16* ph0, const _Float16* ph1,
                                      half8 (&x0)[8], half8 (&x1)[8],
                                      half8 (&h0)[8], half8 (&h1)[8]) {
    asm volatile(
        "global_load_dwordx4 %0, %32, off sc0 sc1\n\t"
        "global_load_dwordx4 %1, %32, off offset:64 sc0 sc1\n\t"
        "global_load_dwordx4 %2, %32, off offset:128 sc0 sc1\n\t"
        "global_load_dwordx4 %3, %32, off offset:192 sc0 sc1\n\t"
        "global_load_dwordx4 %4, %32, off offset:256 sc0 sc1\n\t"
        "global_load_dwordx4 %5, %32, off offset:320 sc0 sc1\n\t"
        "global_load_dwordx4 %6, %32, off offset:384 sc0 sc1\n\t"
        "global_load_dwordx4 %7, %32, off offset:448 sc0 sc1\n\t"
        "global_load_dwordx4 %8, %33, off sc0 sc1\n\t"
        "global_load_dwordx4 %9, %33, off offset:64 sc0 sc1\n\t"
        "global_load_dwordx4 %10, %33, off offset:128 sc0 sc1\n\t"
        "global_load_dwordx4 %11, %33, off offset:192 sc0 sc1\n\t"
        "global_load_dwordx4 %12, %33, off offset:256 sc0 sc1\n\t"
        "global_load_dwordx4 %13, %33, off offset:320 sc0 sc1\n\t"
        "global_load_dwordx4 %14, %33, off offset:384 sc0 sc1\n\t"
        "global_load_dwordx4 %15, %33, off offset:448 sc0 sc1\n\t"
        "global_load_dwordx4 %16, %34, off sc0 sc1\n\t"
        "global_load_dwordx4 %17, %34, off offset:64 sc0 sc1\n\t"
        "global_load_dwordx4 %18, %34, off offset:128 sc0 sc1\n\t"
        "global_load_dwordx4 %19, %34, off offset:192 sc0 sc1\n\t"
        "global_load_dwordx4 %20, %34, off offset:256 sc0 sc1\n\t"
        "global_load_dwordx4 %21, %34, off offset:320 sc0 sc1\n\t"
        "global_load_dwordx4 %22, %34, off offset:384 sc0 sc1\n\t"
        "global_load_dwordx4 %23, %34, off offset:448 sc0 sc1\n\t"
        "global_load_dwordx4 %24, %35, off sc0 sc1\n\t"
        "global_load_dwordx4 %25, %35, off offset:64 sc0 sc1\n\t"
        "global_load_dwordx4 %26, %35, off offset:128 sc0 sc1\n\t"
        "global_load_dwordx4 %27, %35, off offset:192 sc0 sc1\n\t"
        "global_load_dwordx4 %28, %35, off offset:256 sc0 sc1\n\t"
        "global_load_dwordx4 %29, %35, off offset:320 sc0 sc1\n\t"
        "global_load_dwordx4 %30, %35, off offset:384 sc0 sc1\n\t"
        "global_load_dwordx4 %31, %35, off offset:448 sc0 sc1\n\t"
        "s_waitcnt vmcnt(0)"
        : "=&v"(x0[0]), "=&v"(x0[1]), "=&v"(x0[2]), "=&v"(x0[3]),
          "=&v"(x0[4]), "=&v"(x0[5]), "=&v"(x0[6]), "=&v"(x0[7]),
          "=&v"(x1[0]), "=&v"(x1[1]), "=&v"(x1[2]), "=&v"(x1[3]),
          "=&v"(x1[4]), "=&v"(x1[5]), "=&v"(x1[6]), "=&v"(x1[7]),
          "=&v"(h0[0]), "=&v"(h0[1]), "=&v"(h0[2]), "=&v"(h0[3]),
          "=&v"(h0[4]), "=&v"(h0[5]), "=&v"(h0[6]), "=&v"(h0[7]),
          "=&v"(h1[0]), "=&v"(h1[1]), "=&v"(h1[2]), "=&v"(h1[3]),
          "=&v"(h1[4]), "=&v"(h1[5]), "=&v"(h1[6]), "=&v"(h1[7])
        : "v"(px0), "v"(px1), "v"(ph0), "v"(ph1)
        : "memory");
}
// One base, 16 frags (weights, one-time).
__device__ __forceinline__ void ld16w(const _Float16* p, half8 (&r)[16]) {
    asm volatile(
        "global_load_dwordx4 %0, %16, off sc0 sc1\n\t"
        "global_load_dwordx4 %1, %16, off offset:64 sc0 sc1\n\t"
        "global_load_dwordx4 %2, %16, off offset:128 sc0 sc1\n\t"
        "global_load_dwordx4 %3, %16, off offset:192 sc0 sc1\n\t"
        "global_load_dwordx4 %4, %16, off offset:256 sc0 sc1\n\t"
        "global_load_dwordx4 %5, %16, off offset:320 sc0 sc1\n\t"
        "global_load_dwordx4 %6, %16, off offset:384 sc0 sc1\n\t"
        "global_load_dwordx4 %7, %16, off offset:448 sc0 sc1\n\t"
        "global_load_dwordx4 %8, %16, off offset:512 sc0 sc1\n\t"
        "global_load_dwordx4 %9, %16, off offset:576 sc0 sc1\n\t"
        "global_load_dwordx4 %10, %16, off offset:640 sc0 sc1\n\t"
        "global_load_dwordx4 %11, %16, off offset:704 sc0 sc1\n\t"
        "global_load_dwordx4 %12, %16, off offset:768 sc0 sc1\n\t"
        "global_load_dwordx4 %13, %16, off offset:832 sc0 sc1\n\t"
        "global_load_dwordx4 %14, %16, off offset:896 sc0 sc1\n\t"
        "global_load_dwordx4 %15, %16, off offset:960 sc0 sc1\n\t"
        "s_waitcnt vmcnt(0)"
        : "=&v"(r[0]), "=&v"(r[1]), "=&v"(r[2]), "=&v"(r[3]),
          "=&v"(r[4]), "=&v"(r[5]), "=&v"(r[6]), "=&v"(r[7]),
          "=&v"(r[8]), "=&v"(r[9]), "=&v"(r[10]), "=&v"(r[11]),
          "=&v"(r[12]), "=&v"(r[13]), "=&v"(r[14]), "=&v"(r[15])
        : "v"(p)
        : "memory");
}
__device__ __forceinline__ void stcg(_Float16* p, half8 v) {
    asm volatile("global_store_dwordx4 %0, %1, off sc0 sc1" :: "v"(p), "v"(v) : "memory");
}
__device__ __forceinline__ void vdrain() {
    asm volatile("s_waitcnt vmcnt(0)" ::: "memory");
}

// bar layout (ints, memset 0 each launch):
//   bar[32]              init-barrier counter (one-time RMW)
//   bar[64 + l*16 + s]   prog[l][s]: completed steps of block (l,s)
//                        (one 64B line per layer; 16 distinct 4B words)

__global__ __launch_bounds__(256, 1) void lstm_wavefront(
    const int* __restrict__ xind,     // [128][256]
    const float* __restrict__ emb,    // [50000][256]
    const float* __restrict__ W0, const float* __restrict__ U0,
    const float* __restrict__ b0,
    const float* __restrict__ Wsh, const float* __restrict__ Ush,
    const float* __restrict__ bsh,
    const float* __restrict__ fcW, const float* __restrict__ fcb,
    float* __restrict__ out,          // [128][10]
    _Float16* __restrict__ wt,        // ws: [2][1024][512] transposed fp16 weights
    _Float16* __restrict__ hbuf,      // ws: [12][ring][128][256] h ring
    float* __restrict__ h32,          // ws: [128][256] final h fp32
    int* __restrict__ bar,            // ws: counters (memset 0)
    int ring, int hmask)
{
    const int l    = blockIdx.x >> 4;
    const int s    = blockIdx.x & 15;
    const int wave = threadIdx.x >> 6;
    const int lane = threadIdx.x & 63;
    const int quad = lane >> 4;
    const int ln   = lane & 15;
    int* const prog = bar + 64;

    __shared__ float tile[32][33];
    __shared__ unsigned short hsm[128][16];

    // ---- phase 0: transpose W/U fp32 [256][1024] -> wt fp16 [set][n][k] ----
    {
        const int rr = threadIdx.x >> 5;
        const int cc = threadIdx.x & 31;
        const int nl = threadIdx.x >> 3;
        const int kg = threadIdx.x & 7;
        for (int tidx = blockIdx.x; tidx < 1024; tidx += NBLK) {
            const int job   = tidx >> 8;        // 0:W0 1:U0 2:Ws 3:Us
            const int tk    = (tidx >> 5) & 7;
            const int tn    = tidx & 31;
            const float* src = (job == 0) ? W0 : (job == 1) ? U0 : (job == 2) ? Wsh : Ush;
            const int set   = job >> 1;
            const int khalf = job & 1;
            __syncthreads();
            #pragma unroll
            for (int r = 0; r < 4; ++r)
                tile[rr + r * 8][cc] = src[(size_t)(tk * 32 + rr + r * 8) * 1024 + tn * 32 + cc];
            __syncthreads();
            U8 pk;
            #pragma unroll
            for (int j = 0; j < 4; ++j)
                pk.h[j] = (_Float16)tile[kg * 4 + j][nl];
            __hip_atomic_store(
                (unsigned long long*)(wt + ((size_t)(set * 1024 + tn * 32 + nl)) * 512
                                      + khalf * 256 + tk * 32 + kg * 4),
                pk.u, __ATOMIC_RELAXED, AGENT);
        }
    }
    // ---- init barrier (one-time) ----
    vdrain();
    __syncthreads();
    if (threadIdx.x == 0) {
        __hip_atomic_fetch_add(&bar[32], 1, __ATOMIC_RELAXED, AGENT);
        while (pld(&bar[32]) < NBLK) __builtin_amdgcn_s_sleep(2);
    }
    __syncthreads();

    // ---- weight fragments -> registers (stay for all 256 steps) ----
    // B-frag for mfma_f32_16x16x32_f16: n = lane&15, k = ks*32 + quad*8 + j
    half8 bf[4][16];
    {
        const int set = (l == 0) ? 0 : 1;
        #pragma unroll
        for (int q = 0; q < 4; ++q)
            ld16w(wt + ((size_t)(set * 1024 + q * 256 + s * 16 + ln)) * 512 + quad * 8,
                  bf[q]);
    }
    float bias_q[4];
    {
        const float* bv = (l == 0) ? b0 : bsh;
        #pragma unroll
        for (int q = 0; q < 4; ++q)
            bias_q[q] = bv[q * 256 + s * 16 + ln];
    }

    float creg[2][4];
    const int rowA = wave * 32 + ln;
    const int col  = s * 16 + ln;
    const int rrow = threadIdx.x >> 1;
    const int rch  = threadIdx.x & 1;

    for (int t = 0; t < SS; ++t) {
        // ---- lane-parallel RMW-free poll (wave 0 only) ----
        // lanes 0-15: pred layer done step t; 16-31: own layer done step t-1;
        // 32-47: next layer consumed the ring slot we are about to overwrite.
        if (wave == 0) {
            const int* pa = &prog[l * 16 + ln];
            int tgt = INT_MIN;
            if (quad == 0) { if (l > 0) { pa = &prog[(l - 1) * 16 + ln]; tgt = t + 1; } }
            else if (quad == 1) { if (t > 0) tgt = t; }
            else if (quad == 2) {
                if (l < LL - 1 && t >= ring) { pa = &prog[(l + 1) * 16 + ln]; tgt = t - ring + 1; }
            }
            while (!__all(pld(pa) >= tgt)) {}
        }
        __syncthreads();

        f32x4 acc[2][4];
        #pragma unroll
        for (int mt = 0; mt < 2; ++mt)
            #pragma unroll
            for (int q = 0; q < 4; ++q)
                acc[mt][q] = (f32x4){0.f, 0.f, 0.f, 0.f};

        if (l == 0) {
            // x = embedding gather (plain cached loads; latency overlaps poll/h)
            const int i0 = xind[rowA * SS + t];
            const int i1 = xind[(rowA + 16) * SS + t];
            const float* e0 = emb + (size_t)i0 * 256 + quad * 8;
            const float* e1 = emb + (size_t)i1 * 256 + quad * 8;
            half8 ah0[8], ah1[8];
            if (t > 0) {
                const _Float16* hs = hbuf + (((size_t)(l * ring + ((t - 1) & hmask))) << 15)
                                   + rowA * 256 + quad * 8;
                ld8x2(hs, hs + 4096, ah0, ah1);
            }
            #pragma unroll
            for (int ks = 0; ks < 8; ++ks) {
                half8 a0 = cvt8(e0 + ks * 32);
                half8 a1 = cvt8(e1 + ks * 32);
                #pragma unroll
                for (int q = 0; q < 4; ++q) {
                    acc[0][q] = __builtin_amdgcn_mfma_f32_16x16x32_f16(a0, bf[q][ks], acc[0][q], 0, 0, 0);
                    acc[1][q] = __builtin_amdgcn_mfma_f32_16x16x32_f16(a1, bf[q][ks], acc[1][q], 0, 0, 0);
                }
            }
            if (t > 0) {
                #pragma unroll
                for (int ks = 0; ks < 8; ++ks) {
                    #pragma unroll
                    for (int q = 0; q < 4; ++q) {
                        acc[0][q] = __builtin_amdgcn_mfma_f32_16x16x32_f16(ah0[ks], bf[q][ks + 8], acc[0][q], 0, 0, 0);
                        acc[1][q] = __builtin_amdgcn_mfma_f32_16x16x32_f16(ah1[ks], bf[q][ks + 8], acc[1][q], 0, 0, 0);
                    }
                }
            }
        } else {
            const _Float16* xs = hbuf + (((size_t)((l - 1) * ring + (t & hmask))) << 15)
                               + rowA * 256 + quad * 8;
            if (t > 0) {
                // merged x+h batch: ONE MALL round trip
                half8 ax0[8], ax1[8], ah0[8], ah1[8];
                const _Float16* hs = hbuf + (((size_t)(l * ring + ((t - 1) & hmask))) << 15)
                                   + rowA * 256 + quad * 8;
                ld8x4(xs, xs + 4096, hs, hs + 4096, ax0, ax1, ah0, ah1);
                #pragma unroll
                for (int ks = 0; ks < 8; ++ks) {
                    #pragma unroll
                    for (int q = 0; q < 4; ++q) {
                        acc[0][q] = __builtin_amdgcn_mfma_f32_16x16x32_f16(ax0[ks], bf[q][ks], acc[0][q], 0, 0, 0);
                        acc[1][q] = __builtin_amdgcn_mfma_f32_16x16x32_f16(ax1[ks], bf[q][ks], acc[1][q], 0, 0, 0);
                    }
                }
                #pragma unroll
                for (int ks = 0; ks < 8; ++ks) {
                    #pragma unroll
                    for (int q = 0; q < 4; ++q) {
                        acc[0][q] = __builtin_amdgcn_mfma_f32_16x16x32_f16(ah0[ks], bf[q][ks + 8], acc[0][q], 0, 0, 0);
                        acc[1][q] = __builtin_amdgcn_mfma_f32_16x16x32_f16(ah1[ks], bf[q][ks + 8], acc[1][q], 0, 0, 0);
                    }
                }
            } else {
                half8 ax0[8], ax1[8];
                ld8x2(xs, xs + 4096, ax0, ax1);
                #pragma unroll
                for (int ks = 0; ks < 8; ++ks) {
                    #pragma unroll
                    for (int q = 0; q < 4; ++q) {
                        acc[0][q] = __builtin_amdgcn_mfma_f32_16x16x32_f16(ax0[ks], bf[q][ks], acc[0][q], 0, 0, 0);
                        acc[1][q] = __builtin_amdgcn_mfma_f32_16x16x32_f16(ax1[ks], bf[q][ks], acc[1][q], 0, 0, 0);
                    }
                }
            }
        }

        // ---- LSTM cell (D layout: col=lane&15, row=quad*4+reg) ----
        #pragma unroll
        for (int mt = 0; mt < 2; ++mt) {
            #pragma unroll
            for (int r = 0; r < 4; ++r) {
                float gi = acc[mt][0][r] + bias_q[0];
                float gf = acc[mt][1][r] + bias_q[1];
                float gg = acc[mt][2][r] + bias_q[2];
                float go = acc[mt][3][r] + bias_q[3];
                float cold = (t == 0) ? 0.0f : creg[mt][r];
                float cnew = sigf(gf) * cold + sigf(gi) * tanhf_fast(gg);
                creg[mt][r] = cnew;
                float h = sigf(go) * tanhf_fast(cnew);
                int row = wave * 32 + mt * 16 + quad * 4 + r;
                _Float16 hh = (_Float16)h;
                hsm[row][ln] = *(unsigned short*)&hh;
                if (l == LL - 1 && t == SS - 1)
                    __hip_atomic_store(&h32[row * 256 + col], h, __ATOMIC_RELAXED, AGENT);
            }
        }
        __syncthreads();
        // repack LDS -> one coherent 16B store per thread
        {
            _Float16* hd = hbuf + (((size_t)(l * ring + (t & hmask))) << 15)
                         + rrow * 256 + s * 16 + rch * 8;
            half8 v = *(const half8*)&hsm[rrow][rch * 8];
            stcg(hd, v);
        }
        vdrain();               // h stores at coherence point
        __syncthreads();        // ... for ALL waves of this block
        if (threadIdx.x == 0)   // publish own word: plain store, no RMW
            __hip_atomic_store(&prog[l * 16 + s], t + 1, __ATOMIC_RELAXED, AGENT);
    }

    // ---- final FC on the 16 layer-11 blocks: block s -> batch rows s*8..s*8+7
    if (l == LL - 1) {
        if (wave == 0)
            while (!__all(pld(&prog[(LL - 1) * 16 + ln]) >= SS)) {}
        __syncthreads();
        int idx = threadIdx.x;
        if (idx < 80) {
            int b = s * 8 + idx / 10, o = idx % 10;
            float a0 = 0.f, a1 = 0.f, a2 = 0.f, a3 = 0.f;
            for (int d = 0; d < 256; d += 4) {
                a0 += __hip_atomic_load(&h32[b * 256 + d + 0], __ATOMIC_RELAXED, AGENT) * fcW[(d + 0) * 10 + o];
                a1 += __hip_atomic_load(&h32[b * 256 + d + 1], __ATOMIC_RELAXED, AGENT) * fcW[(d + 1) * 10 + o];
                a2 += __hip_atomic_load(&h32[b * 256 + d + 2], __ATOMIC_RELAXED, AGENT) * fcW[(d + 2) * 10 + o];
                a3 += __hip_atomic_load(&h32[b * 256 + d + 3], __ATOMIC_RELAXED, AGENT) * fcW[(d + 3) * 10 + o];
            }
            out[b * 10 + o] = fcb[o] + ((a0 + a1) + (a2 + a3));
        }
    }
}

extern "C" void kernel_launch(void* const* d_in, const int* in_sizes, int n_in,
                              void* d_out, int out_size, void* d_ws, size_t ws_size,
                              hipStream_t stream) {
    const int*   xind = (const int*)d_in[0];
    const float* emb  = (const float*)d_in[1];
    const float* W0   = (const float*)d_in[2];
    const float* U0   = (const float*)d_in[3];
    const float* b0   = (const float*)d_in[4];
    const float* Wsh  = (const float*)d_in[5];
    const float* Ush  = (const float*)d_in[6];
    const float* bsh  = (const float*)d_in[7];
    const float* fcW  = (const float*)d_in[8];
    const float* fcb  = (const float*)d_in[9];
    float* out = (float*)d_out;

    const size_t wtB = (size_t)2 * 1024 * 512 * 2;  // 2 MB
    auto need = [&](int r) {
        return wtB + (size_t)LL * r * 128 * 256 * 2 + 131072 + 4096;
    };
    int ring = (ws_size >= need(8)) ? 8 : (ws_size >= need(4)) ? 4 : 2;

    char* ws = (char*)d_ws;
    _Float16* wt   = (_Float16*)ws;
    _Float16* hbuf = (_Float16*)(ws + wtB);
    float*    h32  = (float*)(ws + wtB + (size_t)LL * ring * 128 * 256 * 2);
    int*      bar  = (int*)((char*)h32 + 131072);

    hipMemsetAsync(bar, 0, 4096, stream);
    hipLaunchKernelGGL(lstm_wavefront, dim3(NBLK), dim3(256), 0, stream,
                       xind, emb, W0, U0, b0, Wsh, Ush, bsh, fcW, fcb, out,
                       wt, hbuf, h32, bar, ring, ring - 1);
}

// Round 6
// 3400.479 us; speedup vs baseline: 1.1588x; 1.1588x over previous
//
#include <hip/hip_runtime.h>
#include <limits.h>

// ---------------------------------------------------------------------------
// ShoppingLSTM: 12-layer LSTM (layer0 own weights, layers1..11 shared),
// B=128, S=256, H=EMB=256, OUT=10.
//
// R6: XCD-local exchange. R2/R4/R5 all pinned at ~15 us/tick = 24.6 MB/tick
// of L2-bypassed (sc0 sc1) reads at the ~1.7 TB/s MALL service ceiling.
// Now: layer l's 16 blocks are mapped to one blockIdx residue class (mod 8,
// the expected XCD round-robin); actual XCD placement is verified at runtime
// via s_getreg(HW_REG_XCC_ID) + a published table. XCD-uniform layers use
// sc0-only reads for h and for a mirrored x-tile (one MALL fill per line per
// XCD, 15 L2 hits); x crosses layers via a distributed 4KB-per-block sc1
// prefetch one tick early (pipeline skew 2/layer, hbuf ring=4). sc1 stores
// invalidate the local L2 line, so sc0 re-reads are never stale. Layers that
// fail the placement check fall back to the R5 path (bit-identical output).
// ---------------------------------------------------------------------------

#define BB 128
#define SS 256
#define LL 12
#define NGRID 256
#define NWORK 192
#define RING 4
#define AGENT __HIP_MEMORY_SCOPE_AGENT

typedef _Float16 half8 __attribute__((ext_vector_type(8)));
typedef float f32x4 __attribute__((ext_vector_type(4)));

union U8 { unsigned long long u; _Float16 h[4]; };

__device__ __forceinline__ float sigf(float x) {
    return 1.0f / (1.0f + __expf(-x));
}
__device__ __forceinline__ float tanhf_fast(float x) {
    return 1.0f - 2.0f / (1.0f + __expf(2.0f * x));
}
__device__ __forceinline__ half8 cvt8(const float* p) {
    float4 u = *(const float4*)p;
    float4 v = *(const float4*)(p + 4);
    half8 h;
    h[0] = (_Float16)u.x; h[1] = (_Float16)u.y; h[2] = (_Float16)u.z; h[3] = (_Float16)u.w;
    h[4] = (_Float16)v.x; h[5] = (_Float16)v.y; h[6] = (_Float16)v.z; h[7] = (_Float16)v.w;
    return h;
}
__device__ __forceinline__ int pld(const int* p) {
    return __hip_atomic_load(p, __ATOMIC_RELAXED, AGENT);
}

// ---- batched loads: loads + terminal waitcnt in ONE asm (R3 lesson) --------
// FAST path: 32 sc0-only loads (x from XCD-local mirror, h from local hbuf)
// + 1 sc1 prefetch load (next tick's x slice from pred's hbuf at MALL).
__device__ __forceinline__ void ld33(const _Float16* px0, const _Float16* px1,
                                     const _Float16* ph0, const _Float16* ph1,
                                     const _Float16* pf,
                                     half8 (&x0)[8], half8 (&x1)[8],
                                     half8 (&h0)[8], half8 (&h1)[8],
                                     half8 &pfv) {
    asm volatile(
        "global_load_dwordx4 %0, %33, off sc0\n\t"
        "global_load_dwordx4 %1, %33, off offset:64 sc0\n\t"
        "global_load_dwordx4 %2, %33, off offset:128 sc0\n\t"
        "global_load_dwordx4 %3, %33, off offset:192 sc0\n\t"
        "global_load_dwordx4 %4, %33, off offset:256 sc0\n\t"
        "global_load_dwordx4 %5, %33, off offset:320 sc0\n\t"
        "global_load_dwordx4 %6, %33, off offset:384 sc0\n\t"
        "global_load_dwordx4 %7, %33, off offset:448 sc0\n\t"
        "global_load_dwordx4 %8, %34, off sc0\n\t"
        "global_load_dwordx4 %9, %34, off offset:64 sc0\n\t"
        "global_load_dwordx4 %10, %34, off offset:128 sc0\n\t"
        "global_load_dwordx4 %11, %34, off offset:192 sc0\n\t"
        "global_load_dwordx4 %12, %34, off offset:256 sc0\n\t"
        "global_load_dwordx4 %13, %34, off offset:320 sc0\n\t"
        "global_load_dwordx4 %14, %34, off offset:384 sc0\n\t"
        "global_load_dwordx4 %15, %34, off offset:448 sc0\n\t"
        "global_load_dwordx4 %16, %35, off sc0\n\t"
        "global_load_dwordx4 %17, %35, off offset:64 sc0\n\t"
        "global_load_dwordx4 %18, %35, off offset:128 sc0\n\t"
        "global_load_dwordx4 %19, %35, off offset:192 sc0\n\t"
        "global_load_dwordx4 %20, %35, off offset:256 sc0\n\t"
        "global_load_dwordx4 %21, %35, off offset:320 sc0\n\t"
        "global_load_dwordx4 %22, %35, off offset:384 sc0\n\t"
        "global_load_dwordx4 %23, %35, off offset:448 sc0\n\t"
        "global_load_dwordx4 %24, %36, off sc0\n\t"
        "global_load_dwordx4 %25, %36, off offset:64 sc0\n\t"
        "global_load_dwordx4 %26, %36, off offset:128 sc0\n\t"
        "global_load_dwordx4 %27, %36, off offset:192 sc0\n\t"
        "global_load_dwordx4 %28, %36, off offset:256 sc0\n\t"
        "global_load_dwordx4 %29, %36, off offset:320 sc0\n\t"
        "global_load_dwordx4 %30, %36, off offset:384 sc0\n\t"
        "global_load_dwordx4 %31, %36, off offset:448 sc0\n\t"
        "global_load_dwordx4 %32, %37, off sc0 sc1\n\t"
        "s_waitcnt vmcnt(0)"
        : "=&v"(x0[0]), "=&v"(x0[1]), "=&v"(x0[2]), "=&v"(x0[3]),
          "=&v"(x0[4]), "=&v"(x0[5]), "=&v"(x0[6]), "=&v"(x0[7]),
          "=&v"(x1[0]), "=&v"(x1[1]), "=&v"(x1[2]), "=&v"(x1[3]),
          "=&v"(x1[4]), "=&v"(x1[5]), "=&v"(x1[6]), "=&v"(x1[7]),
          "=&v"(h0[0]), "=&v"(h0[1]), "=&v"(h0[2]), "=&v"(h0[3]),
          "=&v"(h0[4]), "=&v"(h0[5]), "=&v"(h0[6]), "=&v"(h0[7]),
          "=&v"(h1[0]), "=&v"(h1[1]), "=&v"(h1[2]), "=&v"(h1[3]),
          "=&v"(h1[4]), "=&v"(h1[5]), "=&v"(h1[6]), "=&v"(h1[7]),
          "=&v"(pfv)
        : "v"(px0), "v"(px1), "v"(ph0), "v"(ph1), "v"(pf)
        : "memory");
}
// FAST layer-0: h only, sc0.
__device__ __forceinline__ void ld16h_sc0(const _Float16* p0, const _Float16* p1,
                                          half8 (&r0)[8], half8 (&r1)[8]) {
    asm volatile(
        "global_load_dwordx4 %0, %16, off sc0\n\t"
        "global_load_dwordx4 %1, %16, off offset:64 sc0\n\t"
        "global_load_dwordx4 %2, %16, off offset:128 sc0\n\t"
        "global_load_dwordx4 %3, %16, off offset:192 sc0\n\t"
        "global_load_dwordx4 %4, %16, off offset:256 sc0\n\t"
        "global_load_dwordx4 %5, %16, off offset:320 sc0\n\t"
        "global_load_dwordx4 %6, %16, off offset:384 sc0\n\t"
        "global_load_dwordx4 %7, %16, off offset:448 sc0\n\t"
        "global_load_dwordx4 %8, %17, off sc0\n\t"
        "global_load_dwordx4 %9, %17, off offset:64 sc0\n\t"
        "global_load_dwordx4 %10, %17, off offset:128 sc0\n\t"
        "global_load_dwordx4 %11, %17, off offset:192 sc0\n\t"
        "global_load_dwordx4 %12, %17, off offset:256 sc0\n\t"
        "global_load_dwordx4 %13, %17, off offset:320 sc0\n\t"
        "global_load_dwordx4 %14, %17, off offset:384 sc0\n\t"
        "global_load_dwordx4 %15, %17, off offset:448 sc0\n\t"
        "s_waitcnt vmcnt(0)"
        : "=&v"(r0[0]), "=&v"(r0[1]), "=&v"(r0[2]), "=&v"(r0[3]),
          "=&v"(r0[4]), "=&v"(r0[5]), "=&v"(r0[6]), "=&v"(r0[7]),
          "=&v"(r1[0]), "=&v"(r1[1]), "=&v"(r1[2]), "=&v"(r1[3]),
          "=&v"(r1[4]), "=&v"(r1[5]), "=&v"(r1[6]), "=&v"(r1[7])
        : "v"(p0), "v"(p1)
        : "memory");
}
// SLOW paths (R5, proven): sc0 sc1 everywhere.
__device__ __forceinline__ void ld8x2(const _Float16* p0, const _Float16* p1,
                                      half8 (&r0)[8], half8 (&r1)[8]) {
    asm volatile(
        "global_load_dwordx4 %0, %16, off sc0 sc1\n\t"
        "global_load_dwordx4 %1, %16, off offset:64 sc0 sc1\n\t"
        "global_load_dwordx4 %2, %16, off offset:128 sc0 sc1\n\t"
        "global_load_dwordx4 %3, %16, off offset:192 sc0 sc1\n\t"
        "global_load_dwordx4 %4, %16, off offset:256 sc0 sc1\n\t"
        "global_load_dwordx4 %5, %16, off offset:320 sc0 sc1\n\t"
        "global_load_dwordx4 %6, %16, off offset:384 sc0 sc1\n\t"
        "global_load_dwordx4 %7, %16, off offset:448 sc0 sc1\n\t"
        "global_load_dwordx4 %8, %17, off sc0 sc1\n\t"
        "global_load_dwordx4 %9, %17, off offset:64 sc0 sc1\n\t"
        "global_load_dwordx4 %10, %17, off offset:128 sc0 sc1\n\t"
        "global_load_dwordx4 %11, %17, off offset:192 sc0 sc1\n\t"
        "global_load_dwordx4 %12, %17, off offset:256 sc0 sc1\n\t"
        "global_load_dwordx4 %13, %17, off offset:320 sc0 sc1\n\t"
        "global_load_dwordx4 %14, %17, off offset:384 sc0 sc1\n\t"
        "global_load_dwordx4 %15, %17, off offset:448 sc0 sc1\n\t"
        "s_waitcnt vmcnt(0)"
        : "=&v"(r0[0]), "=&v"(r0[1]), "=&v"(r0[2]), "=&v"(r0[3]),
          "=&v"(r0[4]), "=&v"(r0[5]), "=&v"(r0[6]), "=&v"(r0[7]),
          "=&v"(r1[0]), "=&v"(r1[1]), "=&v"(r1[2]), "=&v"(r1[3]),
          "=&v"(r1[4]), "=&v"(r1[5]), "=&v"(r1[6]), "=&v"(r1[7])
        : "v"(p0), "v"(p1)
        : "memory");
}
__device__ __forceinline__ void ld8x4(const _Float16* px0, const _Float16* px1,
                                      const _Float16* ph0, const _Float16* ph1,
                                      half8 (&x0)[8], half8 (&x1)[8],
                                      half8 (&h0)[8], half8 (&h1)[8]) {
    asm volatile(
        "global_load_dwordx4 %0, %32, off sc0 sc1\n\t"
        "global_load_dwordx4 %1, %32, off offset:64 sc0 sc1\n\t"
        "global_load_dwordx4 %2, %32, off offset:128 sc0 sc1\n\t"
        "global_load_dwordx4 %3, %32, off offset:192 sc0 sc1\n\t"
        "global_load_dwordx4 %4, %32, off offset:256 sc0 sc1\n\t"
        "global_load_dwordx4 %5, %32, off offset:320 sc0 sc1\n\t"
        "global_load_dwordx4 %6, %32, off offset:384 sc0 sc1\n\t"
        "global_load_dwordx4 %7, %32, off offset:448 sc0 sc1\n\t"
        "global_load_dwordx4 %8, %33, off sc0 sc1\n\t"
        "global_load_dwordx4 %9, %33, off offset:64 sc0 sc1\n\t"
        "global_load_dwordx4 %10, %33, off offset:128 sc0 sc1\n\t"
        "global_load_dwordx4 %11, %33, off offset:192 sc0 sc1\n\t"
        "global_load_dwordx4 %12, %33, off offset:256 sc0 sc1\n\t"
        "global_load_dwordx4 %13, %33, off offset:320 sc0 sc1\n\t"
        "global_load_dwordx4 %14, %33, off offset:384 sc0 sc1\n\t"
        "global_load_dwordx4 %15, %33, off offset:448 sc0 sc1\n\t"
        "global_load_dwordx4 %16, %34, off sc0 sc1\n\t"
        "global_load_dwordx4 %17, %34, off offset:64 sc0 sc1\n\t"
        "global_load_dwordx4 %18, %34, off offset:128 sc0 sc1\n\t"
        "global_load_dwordx4 %19, %34, off offset:192 sc0 sc1\n\t"
        "global_load_dwordx4 %20, %34, off offset:256 sc0 sc1\n\t"
        "global_load_dwordx4 %21, %34, off offset:320 sc0 sc1\n\t"
        "global_load_dwordx4 %22, %34, off offset:384 sc0 sc1\n\t"
        "global_load_dwordx4 %23, %34, off offset:448 sc0 sc1\n\t"
        "global_load_dwordx4 %24, %35, off sc0 sc1\n\t"
        "global_load_dwordx4 %25, %35, off offset:64 sc0 sc1\n\t"
        "global_load_dwordx4 %26, %35, off offset:128 sc0 sc1\n\t"
        "global_load_dwordx4 %27, %35, off offset:192 sc0 sc1\n\t"
        "global_load_dwordx4 %28, %35, off offset:256 sc0 sc1\n\t"
        "global_load_dwordx4 %29, %35, off offset:320 sc0 sc1\n\t"
        "global_load_dwordx4 %30, %35, off offset:384 sc0 sc1\n\t"
        "global_load_dwordx4 %31, %35, off offset:448 sc0 sc1\n\t"
        "s_waitcnt vmcnt(0)"
        : "=&v"(x0[0]), "=&v"(x0[1]), "=&v"(x0[2]), "=&v"(x0[3]),
          "=&v"(x0[4]), "=&v"(x0[5]), "=&v"(x0[6]), "=&v"(x0[7]),
          "=&v"(x1[0]), "=&v"(x1[1]), "=&v"(x1[2]), "=&v"(x1[3]),
          "=&v"(x1[4]), "=&v"(x1[5]), "=&v"(x1[6]), "=&v"(x1[7]),
          "=&v"(h0[0]), "=&v"(h0[1]), "=&v"(h0[2]), "=&v"(h0[3]),
          "=&v"(h0[4]), "=&v"(h0[5]), "=&v"(h0[6]), "=&v"(h0[7]),
          "=&v"(h1[0]), "=&v"(h1[1]), "=&v"(h1[2]), "=&v"(h1[3]),
          "=&v"(h1[4]), "=&v"(h1[5]), "=&v"(h1[6]), "=&v"(h1[7])
        : "v"(px0), "v"(px1), "v"(ph0), "v"(ph1)
        : "memory");
}
__device__ __forceinline__ void ld16w(const _Float16* p, half8 (&r)[16]) {
    asm volatile(
        "global_load_dwordx4 %0, %16, off sc0 sc1\n\t"
        "global_load_dwordx4 %1, %16, off offset:64 sc0 sc1\n\t"
        "global_load_dwordx4 %2, %16, off offset:128 sc0 sc1\n\t"
        "global_load_dwordx4 %3, %16, off offset:192 sc0 sc1\n\t"
        "global_load_dwordx4 %4, %16, off offset:256 sc0 sc1\n\t"
        "global_load_dwordx4 %5, %16, off offset:320 sc0 sc1\n\t"
        "global_load_dwordx4 %6, %16, off offset:384 sc0 sc1\n\t"
        "global_load_dwordx4 %7, %16, off offset:448 sc0 sc1\n\t"
        "global_load_dwordx4 %8, %16, off offset:512 sc0 sc1\n\t"
        "global_load_dwordx4 %9, %16, off offset:576 sc0 sc1\n\t"
        "global_load_dwordx4 %10, %16, off offset:640 sc0 sc1\n\t"
        "global_load_dwordx4 %11, %16, off offset:704 sc0 sc1\n\t"
        "global_load_dwordx4 %12, %16, off offset:768 sc0 sc1\n\t"
        "global_load_dwordx4 %13, %16, off offset:832 sc0 sc1\n\t"
        "global_load_dwordx4 %14, %16, off offset:896 sc0 sc1\n\t"
        "global_load_dwordx4 %15, %16, off offset:960 sc0 sc1\n\t"
        "s_waitcnt vmcnt(0)"
        : "=&v"(r[0]), "=&v"(r[1]), "=&v"(r[2]), "=&v"(r[3]),
          "=&v"(r[4]), "=&v"(r[5]), "=&v"(r[6]), "=&v"(r[7]),
          "=&v"(r[8]), "=&v"(r[9]), "=&v"(r[10]), "=&v"(r[11]),
          "=&v"(r[12]), "=&v"(r[13]), "=&v"(r[14]), "=&v"(r[15])
        : "v"(p)
        : "memory");
}
__device__ __forceinline__ void ld1cp(const _Float16* p, half8 &v) {
    asm volatile("global_load_dwordx4 %0, %1, off sc0 sc1\n\ts_waitcnt vmcnt(0)"
                 : "=&v"(v) : "v"(p) : "memory");
}
__device__ __forceinline__ void stcg(_Float16* p, half8 v) {
    asm volatile("global_store_dwordx4 %0, %1, off sc0 sc1" :: "v"(p), "v"(v) : "memory");
}
__device__ __forceinline__ void vdrain() {
    asm volatile("s_waitcnt vmcnt(0)" ::: "memory");
}

// bar layout (ints, memset 0 each launch):
//   bar[32]             init-barrier counter (all 256 blocks)
//   bar[48]             barrier-2 counter (192 workers; protects wt->mx overlay)
//   bar[64  + l*16+s]   prog: completed steps of block (l,s)
//   bar[256 + bx]       xcc table (published XCC_ID per block)
//   bar[512 + l*16+s]   bw: bootstrap (x(0) mirrored) flags

__global__ __launch_bounds__(256, 1) void lstm_wavefront(
    const int* __restrict__ xind,
    const float* __restrict__ emb,
    const float* __restrict__ W0, const float* __restrict__ U0,
    const float* __restrict__ b0,
    const float* __restrict__ Wsh, const float* __restrict__ Ush,
    const float* __restrict__ bsh,
    const float* __restrict__ fcW, const float* __restrict__ fcb,
    float* __restrict__ out,
    _Float16* __restrict__ wt,    // ws[0,2MB): weights; AFTER barrier-2 its
                                  // [0,1.5MB) aliases mx[12][2][128][256]
    _Float16* __restrict__ hbuf,  // ws: [12][4][128][256] h ring (sc1 medium)
    float* __restrict__ h32,      // ws: final h fp32 (aliases wt+1.75MB)
    int* __restrict__ bar)
{
    const int bx   = blockIdx.x;
    const int r8   = bx & 7;
    const bool worker = (bx < 128) || (r8 < 4);
    const int l    = (bx < 128) ? r8 : 8 + r8;
    const int s    = (bx < 128) ? (bx >> 3) : ((bx - 128) >> 3);
    const int wave = threadIdx.x >> 6;
    const int lane = threadIdx.x & 63;
    const int quad = lane >> 4;
    const int ln   = lane & 15;
    int* const prog = bar + 64;
    int* const xcc  = bar + 256;
    int* const bw   = bar + 512;
    _Float16* const mx = wt;   // mirror overlays wt after barrier-2

    __shared__ float tile[32][33];
    __shared__ unsigned short hsm[128][16];
    __shared__ int smode;

    // ---- publish my XCD id ----
    int myxcc = 0;
    asm volatile("s_getreg_b32 %0, hwreg(HW_REG_XCC_ID)" : "=s"(myxcc));
    if (threadIdx.x == 0)
        __hip_atomic_store(&xcc[bx], myxcc, __ATOMIC_RELAXED, AGENT);

    // ---- phase 0: transpose W/U fp32 [256][1024] -> wt fp16 [set][n][k] ----
    {
        const int rr = threadIdx.x >> 5;
        const int cc = threadIdx.x & 31;
        const int nl = threadIdx.x >> 3;
        const int kg = threadIdx.x & 7;
        for (int tidx = bx; tidx < 1024; tidx += NGRID) {
            const int job   = tidx >> 8;
            const int tk    = (tidx >> 5) & 7;
            const int tn    = tidx & 31;
            const float* src = (job == 0) ? W0 : (job == 1) ? U0 : (job == 2) ? Wsh : Ush;
            const int set   = job >> 1;
            const int khalf = job & 1;
            __syncthreads();
            #pragma unroll
            for (int r = 0; r < 4; ++r)
                tile[rr + r * 8][cc] = src[(size_t)(tk * 32 + rr + r * 8) * 1024 + tn * 32 + cc];
            __syncthreads();
            U8 pk;
            #pragma unroll
            for (int j = 0; j < 4; ++j)
                pk.h[j] = (_Float16)tile[kg * 4 + j][nl];
            __hip_atomic_store(
                (unsigned long long*)(wt + ((size_t)(set * 1024 + tn * 32 + nl)) * 512
                                      + khalf * 256 + tk * 32 + kg * 4),
                pk.u, __ATOMIC_RELAXED, AGENT);
        }
    }
    // ---- init barrier (all 256 blocks) ----
    vdrain();
    __syncthreads();
    if (threadIdx.x == 0) {
        __hip_atomic_fetch_add(&bar[32], 1, __ATOMIC_RELAXED, AGENT);
        while (pld(&bar[32]) < NGRID) __builtin_amdgcn_s_sleep(2);
    }
    __syncthreads();
    if (!worker) return;   // 64 filler blocks leave

    // ---- mode: is my whole layer on my XCD? (runtime-verified; else slow) --
    {
        const int member = (l < 8) ? (l + 8 * ln) : (128 + (l - 8) + 8 * ln);
        if (wave == 0) {
            int ok = __all(pld(&xcc[member]) == pld(&xcc[bx]));
            if (threadIdx.x == 0) smode = ok;
        }
        __syncthreads();
    }
    const bool fast = (smode != 0);

    // ---- weight fragments -> registers ----
    half8 bf[4][16];
    {
        const int set = (l == 0) ? 0 : 1;
        #pragma unroll
        for (int q = 0; q < 4; ++q)
            ld16w(wt + ((size_t)(set * 1024 + q * 256 + s * 16 + ln)) * 512 + quad * 8,
                  bf[q]);
    }
    float bias_q[4];
    {
        const float* bv = (l == 0) ? b0 : bsh;
        #pragma unroll
        for (int q = 0; q < 4; ++q)
            bias_q[q] = bv[q * 256 + s * 16 + ln];
    }
    // ---- barrier 2 (192 workers): all weights in regs before mx overlay ----
    __syncthreads();
    if (threadIdx.x == 0) {
        __hip_atomic_fetch_add(&bar[48], 1, __ATOMIC_RELAXED, AGENT);
        while (pld(&bar[48]) < NWORK) __builtin_amdgcn_s_sleep(2);
    }
    __syncthreads();

    // ---- bootstrap (fast, l>0): mirror x(0) slice into XCD-local mx ----
    if (fast && l > 0) {
        if (wave == 0) {
            const int* pa = &prog[(l - 1) * 16 + ln];
            while (!__all(pld(pa) >= 1)) {}
        }
        __syncthreads();
        half8 v;
        const _Float16* src = hbuf + ((size_t)((l - 1) * RING) << 15)
                            + ((size_t)(s * 256 + (int)threadIdx.x)) * 8;
        ld1cp(src, v);
        stcg(mx + ((size_t)(l * 2) << 15) + ((size_t)(s * 256 + (int)threadIdx.x)) * 8, v);
        vdrain();
        __syncthreads();
        if (threadIdx.x == 0)
            __hip_atomic_store(&bw[l * 16 + s], 1, __ATOMIC_RELAXED, AGENT);
    }

    float creg[2][4];
    const int rowA = wave * 32 + ln;
    const int col  = s * 16 + ln;
    const int rrow = threadIdx.x >> 1;
    const int rch  = threadIdx.x & 1;

    for (int t = 0; t < SS; ++t) {
        // ---- lane-parallel polls (wave 0) ----
        if (wave == 0) {
            const int* pa = &prog[l * 16 + ln];
            int tgt = INT_MIN;
            if (quad == 0) {
                if (l > 0) { pa = &prog[(l - 1) * 16 + ln];
                             tgt = (t + 2 < SS) ? t + 2 : SS; }
            } else if (quad == 1) {
                if (t == 0) { if (fast && l > 0) { pa = &bw[l * 16 + ln]; tgt = 1; } }
                else tgt = t;
            } else if (quad == 2) {
                if (l < LL - 1 && t >= RING) { pa = &prog[(l + 1) * 16 + ln]; tgt = t - (RING - 1); }
            }
            while (!__all(pld(pa) >= tgt)) {}
        }
        __syncthreads();

        f32x4 acc[2][4];
        #pragma unroll
        for (int mt = 0; mt < 2; ++mt)
            #pragma unroll
            for (int q = 0; q < 4; ++q)
                acc[mt][q] = (f32x4){0.f, 0.f, 0.f, 0.f};

        half8 pfv;
        const _Float16* hs = hbuf + ((size_t)(l * RING + ((t - 1) & (RING - 1))) << 15)
                           + rowA * 256 + quad * 8;   // t=0: garbage slot, unused

        if (l == 0) {
            const int i0 = xind[rowA * SS + t];
            const int i1 = xind[(rowA + 16) * SS + t];
            const float* e0 = emb + (size_t)i0 * 256 + quad * 8;
            const float* e1 = emb + (size_t)i1 * 256 + quad * 8;
            half8 ah0[8], ah1[8];
            if (fast) ld16h_sc0(hs, hs + 4096, ah0, ah1);
            else      ld8x2(hs, hs + 4096, ah0, ah1);
            #pragma unroll
            for (int ks = 0; ks < 8; ++ks) {
                half8 a0 = cvt8(e0 + ks * 32);
                half8 a1 = cvt8(e1 + ks * 32);
                #pragma unroll
                for (int q = 0; q < 4; ++q) {
                    acc[0][q] = __builtin_amdgcn_mfma_f32_16x16x32_f16(a0, bf[q][ks], acc[0][q], 0, 0, 0);
                    acc[1][q] = __builtin_amdgcn_mfma_f32_16x16x32_f16(a1, bf[q][ks], acc[1][q], 0, 0, 0);
                }
            }
            if (t > 0) {
                #pragma unroll
                for (int ks = 0; ks < 8; ++ks) {
                    #pragma unroll
                    for (int q = 0; q < 4; ++q) {
                        acc[0][q] = __builtin_amdgcn_mfma_f32_16x16x32_f16(ah0[ks], bf[q][ks + 8], acc[0][q], 0, 0, 0);
                        acc[1][q] = __builtin_amdgcn_mfma_f32_16x16x32_f16(ah1[ks], bf[q][ks + 8], acc[1][q], 0, 0, 0);
                    }
                }
            }
        } else {
            half8 ax0[8], ax1[8], ah0[8], ah1[8];
            if (fast) {
                const _Float16* xs = mx + ((size_t)(l * 2 + (t & 1)) << 15)
                                   + rowA * 256 + quad * 8;
                const int tc = (t + 1 < SS) ? t + 1 : SS - 1;
                const _Float16* pf = hbuf + ((size_t)((l - 1) * RING + (tc & (RING - 1))) << 15)
                                   + ((size_t)(s * 256 + (int)threadIdx.x)) * 8;
                ld33(xs, xs + 4096, hs, hs + 4096, pf, ax0, ax1, ah0, ah1, pfv);
            } else {
                const _Float16* xs = hbuf + ((size_t)((l - 1) * RING + (t & (RING - 1))) << 15)
                                   + rowA * 256 + quad * 8;
                ld8x4(xs, xs + 4096, hs, hs + 4096, ax0, ax1, ah0, ah1);
            }
            #pragma unroll
            for (int ks = 0; ks < 8; ++ks) {
                #pragma unroll
                for (int q = 0; q < 4; ++q) {
                    acc[0][q] = __builtin_amdgcn_mfma_f32_16x16x32_f16(ax0[ks], bf[q][ks], acc[0][q], 0, 0, 0);
                    acc[1][q] = __builtin_amdgcn_mfma_f32_16x16x32_f16(ax1[ks], bf[q][ks], acc[1][q], 0, 0, 0);
                }
            }
            if (t > 0) {
                #pragma unroll
                for (int ks = 0; ks < 8; ++ks) {
                    #pragma unroll
                    for (int q = 0; q < 4; ++q) {
                        acc[0][q] = __builtin_amdgcn_mfma_f32_16x16x32_f16(ah0[ks], bf[q][ks + 8], acc[0][q], 0, 0, 0);
                        acc[1][q] = __builtin_amdgcn_mfma_f32_16x16x32_f16(ah1[ks], bf[q][ks + 8], acc[1][q], 0, 0, 0);
                    }
                }
            }
        }

        // ---- LSTM cell (D layout: col=lane&15, row=quad*4+reg) ----
        #pragma unroll
        for (int mt = 0; mt < 2; ++mt) {
            #pragma unroll
            for (int r = 0; r < 4; ++r) {
                float gi = acc[mt][0][r] + bias_q[0];
                float gf = acc[mt][1][r] + bias_q[1];
                float gg = acc[mt][2][r] + bias_q[2];
                float go = acc[mt][3][r] + bias_q[3];
                float cold = (t == 0) ? 0.0f : creg[mt][r];
                float cnew = sigf(gf) * cold + sigf(gi) * tanhf_fast(gg);
                creg[mt][r] = cnew;
                float h = sigf(go) * tanhf_fast(cnew);
                int row = wave * 32 + mt * 16 + quad * 4 + r;
                _Float16 hh = (_Float16)h;
                hsm[row][ln] = *(unsigned short*)&hh;
                if (l == LL - 1 && t == SS - 1)
                    __hip_atomic_store(&h32[row * 256 + col], h, __ATOMIC_RELAXED, AGENT);
            }
        }
        __syncthreads();
        // h -> hbuf (sc1 medium: MALL + local-L2 invalidate), mirror store of
        // the prefetched x(t+1) slice (fast only)
        {
            _Float16* hd = hbuf + ((size_t)(l * RING + (t & (RING - 1))) << 15)
                         + rrow * 256 + s * 16 + rch * 8;
            stcg(hd, *(const half8*)&hsm[rrow][rch * 8]);
            if (fast && l > 0)
                stcg(mx + ((size_t)(l * 2 + ((t + 1) & 1)) << 15)
                        + ((size_t)(s * 256 + (int)threadIdx.x)) * 8, pfv);
        }
        vdrain();
        __syncthreads();
        if (threadIdx.x == 0)
            __hip_atomic_store(&prog[l * 16 + s], t + 1, __ATOMIC_RELAXED, AGENT);
    }

    // ---- final FC on the 16 layer-11 blocks ----
    if (l == LL - 1) {
        if (wave == 0)
            while (!__all(pld(&prog[(LL - 1) * 16 + ln]) >= SS)) {}
        __syncthreads();
        int idx = threadIdx.x;
        if (idx < 80) {
            int b = s * 8 + idx / 10, o = idx % 10;
            float a0 = 0.f, a1 = 0.f, a2 = 0.f, a3 = 0.f;
            for (int d = 0; d < 256; d += 4) {
                a0 += __hip_atomic_load(&h32[b * 256 + d + 0], __ATOMIC_RELAXED, AGENT) * fcW[(d + 0) * 10 + o];
                a1 += __hip_atomic_load(&h32[b * 256 + d + 1], __ATOMIC_RELAXED, AGENT) * fcW[(d + 1) * 10 + o];
                a2 += __hip_atomic_load(&h32[b * 256 + d + 2], __ATOMIC_RELAXED, AGENT) * fcW[(d + 2) * 10 + o];
                a3 += __hip_atomic_load(&h32[b * 256 + d + 3], __ATOMIC_RELAXED, AGENT) * fcW[(d + 3) * 10 + o];
            }
            out[b * 10 + o] = fcb[o] + ((a0 + a1) + (a2 + a3));
        }
    }
}

extern "C" void kernel_launch(void* const* d_in, const int* in_sizes, int n_in,
                              void* d_out, int out_size, void* d_ws, size_t ws_size,
                              hipStream_t stream) {
    const int*   xind = (const int*)d_in[0];
    const float* emb  = (const float*)d_in[1];
    const float* W0   = (const float*)d_in[2];
    const float* U0   = (const float*)d_in[3];
    const float* b0   = (const float*)d_in[4];
    const float* Wsh  = (const float*)d_in[5];
    const float* Ush  = (const float*)d_in[6];
    const float* bsh  = (const float*)d_in[7];
    const float* fcW  = (const float*)d_in[8];
    const float* fcb  = (const float*)d_in[9];
    float* out = (float*)d_out;

    // ws: [0,2MB) wt (mx aliases [0,1.5MB); h32 aliases [1.75MB,1.875MB))
    //     [2MB,5MB) hbuf ring-4; [5MB,+4KB) bar. Total 5.005 MB
    //     (R4/R5 ran ring>=4 => ws >= 5.13 MB known).
    char* ws = (char*)d_ws;
    _Float16* wt   = (_Float16*)ws;
    _Float16* hbuf = (_Float16*)(ws + 2097152);
    float*    h32  = (float*)(ws + 1835008);
    int*      bar  = (int*)(ws + 2097152 + 3145728);

    hipMemsetAsync(bar, 0, 4096, stream);
    hipLaunchKernelGGL(lstm_wavefront, dim3(NGRID), dim3(256), 0, stream,
                       xind, emb, W0, U0, b0, Wsh, Ush, bsh, fcW, fcb, out,
                       wt, hbuf, h32, bar);
}